// Round 3
// baseline (1043.591 us; speedup 1.0000x reference)
//
#include <hip/hip_runtime.h>

typedef float f4 __attribute__((ext_vector_type(4)));

#define Gn 4
#define Bn 2
#define Tn 32
#define Cn 128
#define Hn 64
#define Wn 64
#define HC 16
#define WC 16
#define HW (Hn * Wn)

// grid = (g, b, h, whalf, chalf) = 4*2*64*2*2 = 2048 blocks of 512 threads.
// per-thread tile: 4q x 2c x 4w (acc = 32 VGPRs). c-split across grid: no
// duplicate x fetch (x is sliced by c). Lane map: cslot|wl in low 6 bits ->
// every x-load lane address is unique (1 KB useful per instruction).
__global__ __launch_bounds__(512, 2)
void temporal_agg_kernel(const float* __restrict__ x,
                         const float* __restrict__ attn,
                         float* __restrict__ out) {
    const int bid   = blockIdx.x;
    const int chalf = bid & 1;
    const int whalf = (bid >> 1) & 1;
    const int h     = (bid >> 2) & 63;
    const int b     = (bid >> 8) & 1;
    const int g     = bid >> 9;
    const int tid   = threadIdx.x;

    // half-pixel h interpolation: src = 0.25*h - 0.375
    const float chf = 0.25f * (float)h - 0.375f;
    const float h0f = floorf(chf);
    const float fh  = chf - h0f;
    int h0 = (int)h0f;
    int h1 = h0 + 1;
    h0 = min(max(h0, 0), HC - 1);
    h1 = min(max(h1, 0), HC - 1);

    // Ah[kl][j][q]: h-lerped coarse attn for 16 k at a time.
    // j = coarse w col (10 incl halo), q fastest, padded 32->36 (16B-aligned rows)
    __shared__ float Ah[16][10][36];   // 23 KB

    const int wcb = whalf * 8 - 1;     // coarse col of j=0 (edge -> clamped dup)
    const float* abase = attn + (size_t)(g * Bn + b) * (Tn * Tn * HC * WC);

#define PHASE1(kb)                                                          \
    do {                                                                    \
        _Pragma("unroll")                                                   \
        for (int i = 0; i < 4; ++i) {                                       \
            int idx = tid + 512 * i;      /* [0, 2048) */                   \
            int c4 = idx & 3;                                               \
            int kl = (idx >> 2) & 15;                                       \
            int q  = idx >> 6;                                              \
            const float* p = abase + (size_t)(q * Tn + (kb) + kl) * (HC * WC); \
            f4 v0 = *(const f4*)(p + h0 * WC + 4 * c4);                     \
            f4 v1 = *(const f4*)(p + h1 * WC + 4 * c4);                     \
            f4 ah = v0 + fh * (v1 - v0);                                    \
            _Pragma("unroll")                                               \
            for (int e = 0; e < 4; ++e) {                                   \
                int wc = 4 * c4 + e;                                        \
                int j = wc - wcb;                                           \
                if (j >= 0 && j < 10) Ah[kl][j][q] = ah[e];                 \
                if (whalf == 0 && wc == 0)  Ah[kl][0][q] = ah[e];           \
                if (whalf == 1 && wc == 15) Ah[kl][9][q] = ah[e];           \
            }                                                               \
        }                                                                   \
    } while (0)

    // ---- phase 2 lane mapping ----
    const int cslot = tid & 7;          // 8 * 2c = 16 c (this chalf)
    const int wl    = (tid >> 3) & 7;   // 8 * 4w = 32 fine w (this whalf)
    const int qslot = tid >> 6;         // 8 * 4q = 32 q
    const int q0    = qslot * 4;
    const int wfine = whalf * 32 + wl * 4;
    const int off_hw = h * Wn + wfine;
    const int cbase  = g * 32 + chalf * 16 + cslot * 2;

    const float* xb = x + (size_t)b * (Tn * Cn * HW) + (size_t)cbase * HW + off_hw;
    const size_t kstride = (size_t)Cn * HW;

    f4 acc[4][2];
    #pragma unroll
    for (int qq = 0; qq < 4; ++qq) {
        acc[qq][0] = (f4)0.0f;
        acc[qq][1] = (f4)0.0f;
    }

#define LOADX(dst, kk)                                                      \
    do {                                                                    \
        const float* xk = xb + (size_t)(kk) * kstride;                      \
        (dst)[0] = *(const f4*)(xk);                                        \
        (dst)[1] = *(const f4*)(xk + HW);                                   \
    } while (0)

#define COMPUTE(kk, bb)                                                     \
    do {                                                                    \
        f4 t0 = *(const f4*)&Ah[(kk) & 15][wl    ][q0];                     \
        f4 t1 = *(const f4*)&Ah[(kk) & 15][wl + 1][q0];                     \
        f4 t2 = *(const f4*)&Ah[(kk) & 15][wl + 2][q0];                     \
        _Pragma("unroll")                                                   \
        for (int qq = 0; qq < 4; ++qq) {                                    \
            f4 a;                                                           \
            a.x = 0.375f * t0[qq] + 0.625f * t1[qq];                        \
            a.y = 0.125f * t0[qq] + 0.875f * t1[qq];                        \
            a.z = 0.875f * t1[qq] + 0.125f * t2[qq];                        \
            a.w = 0.625f * t1[qq] + 0.375f * t2[qq];                        \
            acc[qq][0] += a * (bb)[0];                                      \
            acc[qq][1] += a * (bb)[1];                                      \
        }                                                                   \
    } while (0)

    f4 buf[3][2];
    // prime x prefetch before phase1 so the loads fly during LDS fill
    LOADX(buf[0], 0);
    LOADX(buf[1], 1);

    PHASE1(0);
    __syncthreads();

    #pragma unroll
    for (int k = 0; k < 16; ++k) {      // loads run to k=17 (next kb's data)
        LOADX(buf[(k + 2) % 3], k + 2);
        COMPUTE(k, buf[k % 3]);
    }

    __syncthreads();
    PHASE1(16);
    __syncthreads();

    #pragma unroll
    for (int k = 16; k < 32; ++k) {
        if (k < 30) LOADX(buf[(k + 2) % 3], k + 2);
        COMPUTE(k, buf[k % 3]);
    }

    // ---- epilogue: nontemporal stores (keep L2/L3 for x) ----
    #pragma unroll
    for (int qq = 0; qq < 4; ++qq) {
        const int q = q0 + qq;
        float* ob = out + ((size_t)(b * Tn + q) * Cn + cbase) * HW + off_hw;
        __builtin_nontemporal_store(acc[qq][0], (f4*)ob);
        __builtin_nontemporal_store(acc[qq][1], (f4*)(ob + HW));
    }
#undef PHASE1
#undef LOADX
#undef COMPUTE
}

extern "C" void kernel_launch(void* const* d_in, const int* in_sizes, int n_in,
                              void* d_out, int out_size, void* d_ws, size_t ws_size,
                              hipStream_t stream) {
    const float* x    = (const float*)d_in[0];
    const float* attn = (const float*)d_in[1];
    float* out        = (float*)d_out;
    temporal_agg_kernel<<<dim3(Gn * Bn * Hn * 2 * 2), dim3(512), 0, stream>>>(x, attn, out);
}